// Round 4
// baseline (113.122 us; speedup 1.0000x reference)
//
#include <hip/hip_runtime.h>
#include <math.h>

#define N_PROP 1000
#define NUM_CLASSES 81
#define NFG 80
#define SCORE_THRESH 0.05f
#define NMS_THRESH 0.5f
#define DET_PER_IMG 100
#define PER_CLASS_CAP 100
#define KEPT_CAP (NFG * PER_CLASS_CAP)   /* 8000, fixed */
// log(1000/16)
#define BBOX_XFORM_CLIP 4.135166556742356f

// ---------------- Kernel A: per-class softmax + decode + sort + NMS -------
// grid = NFG blocks (one class each), 256 threads.
// Writes ALL PER_CLASS_CAP slots for its class every call (survivors by
// survivor-rank, zeros for the rest) -> no global counters, no memsets.
__global__ __launch_bounds__(256) void k_class(
    const float* __restrict__ logits,   // [N_PROP, 81]
    const float* __restrict__ deltas,   // [N_PROP, 324]
    const float* __restrict__ pboxes,   // [N_PROP, 4]
    const int* __restrict__ ih, const int* __restrict__ iw,
    float* __restrict__ keptScore,      // [KEPT_CAP]
    unsigned* __restrict__ keptKey,     // [KEPT_CAP]
    float4* __restrict__ keptBox)       // [KEPT_CAP]
{
    const int c   = blockIdx.x;         // fg class 0..79
    const int cls = c + 1;              // column in logits/deltas
    const int tid = threadIdx.x;

    __shared__ float sm[N_PROP];        // row max
    __shared__ float sd[N_PROP];        // row denom
    __shared__ float ss[N_PROP];        // candidate scores (unsorted)
    __shared__ int   si[N_PROP];        // candidate proposal idx
    __shared__ float sb[N_PROP * 4];    // candidate boxes (unsorted)
    __shared__ float os[N_PROP];        // sorted scores
    __shared__ float ob[N_PROP * 4];    // sorted boxes
    __shared__ int   ok[N_PROP];        // kept flags
    __shared__ int   cnt;

    if (tid == 0) cnt = 0;

    // softmax stats for all 1000 rows (redundant across blocks; logits are
    // L2-resident: 80 x 324 KB re-read ~= 26 MB @ L2 ~ 1 us)
    for (int n = tid; n < N_PROP; n += 256) {
        const float* row = logits + (size_t)n * NUM_CLASSES;
        float m = row[0];
        #pragma unroll 9
        for (int k = 1; k < NUM_CLASSES; ++k) m = fmaxf(m, row[k]);
        float s = 0.0f;
        #pragma unroll 9
        for (int k = 0; k < NUM_CLASSES; ++k) s += expf(row[k] - m);
        sm[n] = m; sd[n] = s;
    }
    __syncthreads();

    const float W = (float)iw[0] - 1.0f;
    const float H = (float)ih[0] - 1.0f;

    // filter + decode + compact (LDS atomic; storage order irrelevant since
    // final order is fixed by the (score desc, n asc) rank sort below)
    for (int n = tid; n < N_PROP; n += 256) {
        const float p = expf(logits[(size_t)n * NUM_CLASSES + cls] - sm[n]) / sd[n];
        if (p > SCORE_THRESH) {
            const float x1b = pboxes[n * 4 + 0];
            const float y1b = pboxes[n * 4 + 1];
            const float x2b = pboxes[n * 4 + 2];
            const float y2b = pboxes[n * 4 + 3];
            const float w  = x2b - x1b + 1.0f;
            const float h  = y2b - y1b + 1.0f;
            const float cx = x1b + 0.5f * w;
            const float cy = y1b + 0.5f * h;
            const float* d = deltas + (size_t)n * (NUM_CLASSES * 4) + cls * 4;
            const float dx = d[0] / 10.0f;
            const float dy = d[1] / 10.0f;
            const float dw = fminf(d[2] / 5.0f, BBOX_XFORM_CLIP);
            const float dh = fminf(d[3] / 5.0f, BBOX_XFORM_CLIP);
            const float pcx = dx * w + cx;
            const float pcy = dy * h + cy;
            const float pw  = expf(dw) * w;
            const float ph  = expf(dh) * h;
            float X1 = pcx - 0.5f * pw;
            float Y1 = pcy - 0.5f * ph;
            float X2 = pcx + 0.5f * pw - 1.0f;
            float Y2 = pcy + 0.5f * ph - 1.0f;
            X1 = fminf(fmaxf(X1, 0.0f), W);
            Y1 = fminf(fmaxf(Y1, 0.0f), H);
            X2 = fminf(fmaxf(X2, 0.0f), W);
            Y2 = fminf(fmaxf(Y2, 0.0f), H);

            const int pos = atomicAdd(&cnt, 1);
            ss[pos] = p;
            si[pos] = n;
            sb[pos * 4 + 0] = X1;
            sb[pos * 4 + 1] = Y1;
            sb[pos * 4 + 2] = X2;
            sb[pos * 4 + 3] = Y2;
        }
    }
    __syncthreads();
    const int M = cnt;

    // rank sort: (score desc, prop_idx asc) — matches stable argsort(-s)
    for (int i = tid; i < M; i += 256) {
        const float s0 = ss[i];
        const int   i0 = si[i];
        int r = 0;
        for (int j = 0; j < M; ++j) {
            const float sj = ss[j];
            r += (sj > s0) || (sj == s0 && si[j] < i0);
        }
        os[r] = s0;
        ob[r * 4 + 0] = sb[i * 4 + 0];
        ob[r * 4 + 1] = sb[i * 4 + 1];
        ob[r * 4 + 2] = sb[i * 4 + 2];
        ob[r * 4 + 3] = sb[i * 4 + 3];
        ok[r] = 1;
    }
    __syncthreads();

    // greedy NMS: sequential over i, parallel suppression of j > i
    for (int i = 0; i < M; ++i) {
        if (ok[i]) {
            const float ax1 = ob[i * 4 + 0], ay1 = ob[i * 4 + 1];
            const float ax2 = ob[i * 4 + 2], ay2 = ob[i * 4 + 3];
            const float aarea = (ax2 - ax1 + 1.0f) * (ay2 - ay1 + 1.0f);
            for (int j = i + 1 + tid; j < M; j += 256) {
                const float bx1 = ob[j * 4 + 0], by1 = ob[j * 4 + 1];
                const float bx2 = ob[j * 4 + 2], by2 = ob[j * 4 + 3];
                const float barea = (bx2 - bx1 + 1.0f) * (by2 - by1 + 1.0f);
                const float ix1 = fmaxf(ax1, bx1), iy1 = fmaxf(ay1, by1);
                const float ix2 = fminf(ax2, bx2), iy2 = fminf(ay2, by2);
                const float iw_ = fmaxf(ix2 - ix1 + 1.0f, 0.0f);
                const float ih_ = fmaxf(iy2 - iy1 + 1.0f, 0.0f);
                const float inter = iw_ * ih_;
                const float iou = inter / (aarea + barea - inter);
                if (iou > NMS_THRESH) ok[j] = 0;
            }
        }
        __syncthreads();
    }

    // write survivors to fixed per-class slots; zero-fill the rest.
    // flatkey = c*1000 + sorted_pos matches ref's cand.reshape(-1) indexing.
    for (int i = tid; i < M; i += 256) {
        if (ok[i]) {
            int sr = 0;
            for (int j = 0; j < i; ++j) sr += ok[j];
            if (sr < PER_CLASS_CAP) {
                const int slot = c * PER_CLASS_CAP + sr;
                keptScore[slot] = os[i];
                keptKey[slot]   = (unsigned)(c * N_PROP + i);
                keptBox[slot]   = make_float4(ob[i * 4 + 0], ob[i * 4 + 1],
                                              ob[i * 4 + 2], ob[i * 4 + 3]);
            }
        }
    }
    // total survivors (every thread computes; M is small, broadcast reads)
    int S = 0;
    for (int j = 0; j < M; ++j) S += ok[j];
    if (S > PER_CLASS_CAP) S = PER_CLASS_CAP;
    for (int s = S + tid; s < PER_CLASS_CAP; s += 256) {
        const int slot = c * PER_CLASS_CAP + s;
        keptScore[slot] = 0.0f;                       // invalid marker
        keptKey[slot]   = (unsigned)(c * N_PROP + s); // distinct key
        keptBox[slot]   = make_float4(0.0f, 0.0f, 0.0f, 0.0f);
    }
}

// ---------------- Kernel B: global top-100 via LDS rank ----------------
// Fixed K = KEPT_CAP = 8000 distinct packed keys; every rank 0..7999 occurs
// exactly once, so ranks 0..99 each get exactly one writer -> d_out fully
// written every call (invalid slots write zeros, matching ref's -inf -> 0).
__global__ __launch_bounds__(256) void k_topk(
    const float* __restrict__ keptScore,
    const unsigned* __restrict__ keptKey,
    const float4* __restrict__ keptBox,
    float* __restrict__ out)            // [100] scores | [400] boxes | [100] labels
{
    __shared__ unsigned long long pk[KEPT_CAP];
    const int blockStart = blockIdx.x * 64;

    for (int j = threadIdx.x; j < KEPT_CAP; j += 256) {
        pk[j] = ((unsigned long long)__float_as_uint(keptScore[j]) << 32)
              | (unsigned)(~keptKey[j]);
    }
    __syncthreads();

    const int e    = blockStart + (threadIdx.x >> 2);
    const int part = threadIdx.x & 3;
    const unsigned long long mykey = pk[e];

    const int lo = (KEPT_CAP * part) >> 2;
    const int hi = (KEPT_CAP * (part + 1)) >> 2;
    int r = 0;
    for (int j = lo; j + 8 <= hi; j += 8) {
        const unsigned long long k0 = pk[j + 0];
        const unsigned long long k1 = pk[j + 1];
        const unsigned long long k2 = pk[j + 2];
        const unsigned long long k3 = pk[j + 3];
        const unsigned long long k4 = pk[j + 4];
        const unsigned long long k5 = pk[j + 5];
        const unsigned long long k6 = pk[j + 6];
        const unsigned long long k7 = pk[j + 7];
        r += (int)(k0 > mykey) + (int)(k1 > mykey)
           + (int)(k2 > mykey) + (int)(k3 > mykey)
           + (int)(k4 > mykey) + (int)(k5 > mykey)
           + (int)(k6 > mykey) + (int)(k7 > mykey);
    }

    r += __shfl_xor(r, 1);
    r += __shfl_xor(r, 2);

    if (part == 0 && r < DET_PER_IMG) {
        const float sc = keptScore[e];
        const bool valid = sc > 0.0f;
        out[r] = sc;                                   // 0 when invalid
        const float4 b = keptBox[e];                   // zeros when invalid
        out[DET_PER_IMG + r * 4 + 0] = b.x;
        out[DET_PER_IMG + r * 4 + 1] = b.y;
        out[DET_PER_IMG + r * 4 + 2] = b.z;
        out[DET_PER_IMG + r * 4 + 3] = b.w;
        const unsigned key = keptKey[e];
        out[DET_PER_IMG * 5 + r] = valid ? (float)(key / N_PROP + 1) : 0.0f;
    }
}

extern "C" void kernel_launch(void* const* d_in, const int* in_sizes, int n_in,
                              void* d_out, int out_size, void* d_ws, size_t ws_size,
                              hipStream_t stream) {
    const float* logits = (const float*)d_in[0];
    const float* deltas = (const float*)d_in[1];
    const float* pboxes = (const float*)d_in[2];
    const int*   ih     = (const int*)d_in[3];
    const int*   iw     = (const int*)d_in[4];
    float* out = (float*)d_out;

    // workspace layout (16B-aligned first)
    char* p = (char*)d_ws;
    float4*   keptBox   = (float4*)p;    p += (size_t)KEPT_CAP * 16;
    float*    keptScore = (float*)p;     p += (size_t)KEPT_CAP * 4;
    unsigned* keptKey   = (unsigned*)p;  p += (size_t)KEPT_CAP * 4;

    k_class<<<NFG, 256, 0, stream>>>(logits, deltas, pboxes, ih, iw,
                                     keptScore, keptKey, keptBox);
    k_topk<<<KEPT_CAP / 64, 256, 0, stream>>>(keptScore, keptKey, keptBox, out);
}

// Round 5
// 76.238 us; speedup vs baseline: 1.4838x; 1.4838x over previous
//
#include <hip/hip_runtime.h>
#include <math.h>

#define N_PROP 1000
#define NUM_CLASSES 81
#define NFG 80
#define SCORE_THRESH 0.05f
#define NMS_THRESH 0.5f
#define DET_PER_IMG 100
#define PER_CLASS_CAP 100
#define KEPT_CAP (NFG * PER_CLASS_CAP)   /* 8000, fixed */
// log(1000/16)
#define BBOX_XFORM_CLIP 4.135166556742356f

// ---------------- Kernel 1: parallel softmax + decode -> dense grid -------
// grid = N_PROP blocks, 128 threads. Lane t handles class t for proposal n.
// Writes ALL 80 score slots (0 when below threshold) -> no counters, no
// memset. Boxes written only when above threshold; only those slots are
// ever read (by k_nms, later in the same call) -> deterministic.
__global__ __launch_bounds__(128) void k_decode(
    const float* __restrict__ logits,   // [N_PROP, 81]
    const float* __restrict__ deltas,   // [N_PROP, 324]
    const float* __restrict__ pboxes,   // [N_PROP, 4]
    const int* __restrict__ ih, const int* __restrict__ iw,
    float* __restrict__ candS,          // [NFG][N_PROP]
    float4* __restrict__ candB)         // [NFG][N_PROP]
{
    const int n = blockIdx.x;
    const int t = threadIdx.x;
    __shared__ float redm[2];
    __shared__ float reds[2];

    float l = (t < NUM_CLASSES) ? logits[n * NUM_CLASSES + t] : -INFINITY;

    float m = l;
    #pragma unroll
    for (int o = 32; o > 0; o >>= 1) m = fmaxf(m, __shfl_xor(m, o));
    const int wave = t >> 6;
    if ((t & 63) == 0) redm[wave] = m;
    __syncthreads();
    m = fmaxf(redm[0], redm[1]);

    float e = (t < NUM_CLASSES) ? expf(l - m) : 0.0f;
    float s = e;
    #pragma unroll
    for (int o = 32; o > 0; o >>= 1) s += __shfl_xor(s, o);
    if ((t & 63) == 0) reds[wave] = s;
    __syncthreads();
    s = reds[0] + reds[1];

    if (t >= 1 && t < NUM_CLASSES) {
        const float prob = e / s;
        const int c = t - 1;
        candS[(size_t)c * N_PROP + n] = (prob > SCORE_THRESH) ? prob : 0.0f;
        if (prob > SCORE_THRESH) {
            const float x1b = pboxes[n * 4 + 0];
            const float y1b = pboxes[n * 4 + 1];
            const float x2b = pboxes[n * 4 + 2];
            const float y2b = pboxes[n * 4 + 3];
            const float w  = x2b - x1b + 1.0f;
            const float h  = y2b - y1b + 1.0f;
            const float cx = x1b + 0.5f * w;
            const float cy = y1b + 0.5f * h;
            const float* d = deltas + (size_t)n * (NUM_CLASSES * 4) + t * 4;
            const float dx = d[0] / 10.0f;
            const float dy = d[1] / 10.0f;
            const float dw = fminf(d[2] / 5.0f, BBOX_XFORM_CLIP);
            const float dh = fminf(d[3] / 5.0f, BBOX_XFORM_CLIP);
            const float pcx = dx * w + cx;
            const float pcy = dy * h + cy;
            const float pw  = expf(dw) * w;
            const float ph  = expf(dh) * h;
            float X1 = pcx - 0.5f * pw;
            float Y1 = pcy - 0.5f * ph;
            float X2 = pcx + 0.5f * pw - 1.0f;
            float Y2 = pcy + 0.5f * ph - 1.0f;
            const float W = (float)iw[0] - 1.0f;
            const float H = (float)ih[0] - 1.0f;
            X1 = fminf(fmaxf(X1, 0.0f), W);
            Y1 = fminf(fmaxf(Y1, 0.0f), H);
            X2 = fminf(fmaxf(X2, 0.0f), W);
            Y2 = fminf(fmaxf(Y2, 0.0f), H);
            candB[(size_t)c * N_PROP + n] = make_float4(X1, Y1, X2, Y2);
        }
    }
}

// ---------------- Kernel 2: per-class compact + sort + greedy NMS ---------
// grid = NFG blocks, 256 threads. Writes ALL PER_CLASS_CAP slots for its
// class (survivors by survivor-rank, zeros for the rest).
__global__ __launch_bounds__(256) void k_nms(
    const float* __restrict__ candS,
    const float4* __restrict__ candB,
    float* __restrict__ keptScore,      // [KEPT_CAP]
    unsigned* __restrict__ keptKey,     // [KEPT_CAP]
    float4* __restrict__ keptBox)       // [KEPT_CAP]
{
    const int c = blockIdx.x;
    const int tid = threadIdx.x;

    __shared__ float ss[N_PROP];
    __shared__ int   si[N_PROP];
    __shared__ float sb[N_PROP * 4];
    __shared__ float os[N_PROP];
    __shared__ float ob[N_PROP * 4];
    __shared__ int   ok[N_PROP];
    __shared__ int   cnt;

    if (tid == 0) cnt = 0;
    __syncthreads();

    // compact candidates (coalesced score read; gather boxes for hits only)
    for (int n = tid; n < N_PROP; n += 256) {
        const float p = candS[(size_t)c * N_PROP + n];
        if (p > SCORE_THRESH) {
            const float4 b = candB[(size_t)c * N_PROP + n];
            const int pos = atomicAdd(&cnt, 1);
            ss[pos] = p;
            si[pos] = n;
            sb[pos * 4 + 0] = b.x;
            sb[pos * 4 + 1] = b.y;
            sb[pos * 4 + 2] = b.z;
            sb[pos * 4 + 3] = b.w;
        }
    }
    __syncthreads();
    const int M = cnt;

    // rank sort: (score desc, prop_idx asc) — matches stable argsort(-s)
    for (int i = tid; i < M; i += 256) {
        const float s0 = ss[i];
        const int   i0 = si[i];
        int r = 0;
        for (int j = 0; j < M; ++j) {
            const float sj = ss[j];
            r += (sj > s0) || (sj == s0 && si[j] < i0);
        }
        os[r] = s0;
        ob[r * 4 + 0] = sb[i * 4 + 0];
        ob[r * 4 + 1] = sb[i * 4 + 1];
        ob[r * 4 + 2] = sb[i * 4 + 2];
        ob[r * 4 + 3] = sb[i * 4 + 3];
        ok[r] = 1;
    }
    __syncthreads();

    // greedy NMS: sequential over i, parallel suppression of j > i
    for (int i = 0; i < M; ++i) {
        if (ok[i]) {
            const float ax1 = ob[i * 4 + 0], ay1 = ob[i * 4 + 1];
            const float ax2 = ob[i * 4 + 2], ay2 = ob[i * 4 + 3];
            const float aarea = (ax2 - ax1 + 1.0f) * (ay2 - ay1 + 1.0f);
            for (int j = i + 1 + tid; j < M; j += 256) {
                const float bx1 = ob[j * 4 + 0], by1 = ob[j * 4 + 1];
                const float bx2 = ob[j * 4 + 2], by2 = ob[j * 4 + 3];
                const float barea = (bx2 - bx1 + 1.0f) * (by2 - by1 + 1.0f);
                const float ix1 = fmaxf(ax1, bx1), iy1 = fmaxf(ay1, by1);
                const float ix2 = fminf(ax2, bx2), iy2 = fminf(ay2, by2);
                const float iw_ = fmaxf(ix2 - ix1 + 1.0f, 0.0f);
                const float ih_ = fmaxf(iy2 - iy1 + 1.0f, 0.0f);
                const float inter = iw_ * ih_;
                const float iou = inter / (aarea + barea - inter);
                if (iou > NMS_THRESH) ok[j] = 0;
            }
        }
        __syncthreads();
    }

    // write survivors to fixed per-class slots; zero-fill the rest.
    for (int i = tid; i < M; i += 256) {
        if (ok[i]) {
            int sr = 0;
            for (int j = 0; j < i; ++j) sr += ok[j];
            if (sr < PER_CLASS_CAP) {
                const int slot = c * PER_CLASS_CAP + sr;
                keptScore[slot] = os[i];
                keptKey[slot]   = (unsigned)(c * N_PROP + i);
                keptBox[slot]   = make_float4(ob[i * 4 + 0], ob[i * 4 + 1],
                                              ob[i * 4 + 2], ob[i * 4 + 3]);
            }
        }
    }
    int S = 0;
    for (int j = 0; j < M; ++j) S += ok[j];
    if (S > PER_CLASS_CAP) S = PER_CLASS_CAP;
    for (int s = S + tid; s < PER_CLASS_CAP; s += 256) {
        const int slot = c * PER_CLASS_CAP + s;
        keptScore[slot] = 0.0f;                       // invalid marker
        keptKey[slot]   = (unsigned)(c * N_PROP + s); // distinct key
        keptBox[slot]   = make_float4(0.0f, 0.0f, 0.0f, 0.0f);
    }
}

// ---------------- Kernel 3: global top-100 via LDS rank ----------------
// Fixed K = 8000 distinct packed keys; ranks 0..99 each get exactly one
// writer -> d_out fully written every call.
__global__ __launch_bounds__(256) void k_topk(
    const float* __restrict__ keptScore,
    const unsigned* __restrict__ keptKey,
    const float4* __restrict__ keptBox,
    float* __restrict__ out)            // [100] scores | [400] boxes | [100] labels
{
    __shared__ unsigned long long pk[KEPT_CAP];
    const int blockStart = blockIdx.x * 64;

    for (int j = threadIdx.x; j < KEPT_CAP; j += 256) {
        pk[j] = ((unsigned long long)__float_as_uint(keptScore[j]) << 32)
              | (unsigned)(~keptKey[j]);
    }
    __syncthreads();

    const int e    = blockStart + (threadIdx.x >> 2);
    const int part = threadIdx.x & 3;
    const unsigned long long mykey = pk[e];

    const int lo = (KEPT_CAP * part) >> 2;
    const int hi = (KEPT_CAP * (part + 1)) >> 2;
    int r = 0;
    for (int j = lo; j + 8 <= hi; j += 8) {
        const unsigned long long k0 = pk[j + 0];
        const unsigned long long k1 = pk[j + 1];
        const unsigned long long k2 = pk[j + 2];
        const unsigned long long k3 = pk[j + 3];
        const unsigned long long k4 = pk[j + 4];
        const unsigned long long k5 = pk[j + 5];
        const unsigned long long k6 = pk[j + 6];
        const unsigned long long k7 = pk[j + 7];
        r += (int)(k0 > mykey) + (int)(k1 > mykey)
           + (int)(k2 > mykey) + (int)(k3 > mykey)
           + (int)(k4 > mykey) + (int)(k5 > mykey)
           + (int)(k6 > mykey) + (int)(k7 > mykey);
    }

    r += __shfl_xor(r, 1);
    r += __shfl_xor(r, 2);

    if (part == 0 && r < DET_PER_IMG) {
        const float sc = keptScore[e];
        const bool valid = sc > 0.0f;
        out[r] = sc;
        const float4 b = keptBox[e];
        out[DET_PER_IMG + r * 4 + 0] = b.x;
        out[DET_PER_IMG + r * 4 + 1] = b.y;
        out[DET_PER_IMG + r * 4 + 2] = b.z;
        out[DET_PER_IMG + r * 4 + 3] = b.w;
        const unsigned key = keptKey[e];
        out[DET_PER_IMG * 5 + r] = valid ? (float)(key / N_PROP + 1) : 0.0f;
    }
}

extern "C" void kernel_launch(void* const* d_in, const int* in_sizes, int n_in,
                              void* d_out, int out_size, void* d_ws, size_t ws_size,
                              hipStream_t stream) {
    const float* logits = (const float*)d_in[0];
    const float* deltas = (const float*)d_in[1];
    const float* pboxes = (const float*)d_in[2];
    const int*   ih     = (const int*)d_in[3];
    const int*   iw     = (const int*)d_in[4];
    float* out = (float*)d_out;

    // workspace layout (16B-aligned chunks first)
    char* p = (char*)d_ws;
    float4*   candB     = (float4*)p;    p += (size_t)NFG * N_PROP * 16;
    float4*   keptBox   = (float4*)p;    p += (size_t)KEPT_CAP * 16;
    float*    candS     = (float*)p;     p += (size_t)NFG * N_PROP * 4;
    float*    keptScore = (float*)p;     p += (size_t)KEPT_CAP * 4;
    unsigned* keptKey   = (unsigned*)p;  p += (size_t)KEPT_CAP * 4;

    k_decode<<<N_PROP, 128, 0, stream>>>(logits, deltas, pboxes, ih, iw, candS, candB);
    k_nms<<<NFG, 256, 0, stream>>>(candS, candB, keptScore, keptKey, keptBox);
    k_topk<<<KEPT_CAP / 64, 256, 0, stream>>>(keptScore, keptKey, keptBox, out);
}